// Round 3
// baseline (620.647 us; speedup 1.0000x reference)
//
#include <hip/hip_runtime.h>
#include <math.h>

#define BN 8
#define DDIM 256
#define MEMN 131072
#define CWN 64
#define RN 4
#define CN 25
#define DELTA_C 0.005f
#define EPS_C 1e-6f
#define RPB 1024
#define NBLK (MEMN / RPB)   // 128
#define NEG_INF (-3.402823466e38f)
#define IMAX 0x7fffffff

// ---------- helpers ----------

__device__ inline void wave_reduce_max(float& v, int& i, int& t) {
#pragma unroll
  for (int off = 32; off; off >>= 1) {
    float ov = __shfl_down(v, off);
    int oi = __shfl_down(i, off);
    int ot = __shfl_down(t, off);
    if (ov > v || (ov == v && oi < i)) { v = ov; i = oi; t = ot; }
  }
}

// block of 256 threads; returns (max value, min index on tie) + winning tid
__device__ inline void block_argmax256(int tid, float v, int i, int t,
                                       float& rv, int& ri, int& rt) {
  __shared__ float sv[4];
  __shared__ int si[4], st[4];
  __shared__ float bv;
  __shared__ int bi, bt;
  wave_reduce_max(v, i, t);
  if ((tid & 63) == 0) { int w = tid >> 6; sv[w] = v; si[w] = i; st[w] = t; }
  __syncthreads();
  if (tid == 0) {
    float xv = sv[0]; int xi = si[0], xt = st[0];
#pragma unroll
    for (int w = 1; w < 4; w++)
      if (sv[w] > xv || (sv[w] == xv && si[w] < xi)) { xv = sv[w]; xi = si[w]; xt = st[w]; }
    bv = xv; bi = xi; bt = xt;
  }
  __syncthreads();
  rv = bv; ri = bi; rt = bt;
  __syncthreads();
}

// top-4 indices of 8 nonneg values padded with zero-candidates at idx 8..11
// (JAX top_k: value desc, index asc on ties)
__device__ inline void top4_of8(const float* v8, int* out4) {
  float val[12]; int idx[12]; bool used[12];
#pragma unroll
  for (int i = 0; i < 12; i++) { val[i] = (i < 8) ? v8[i] : 0.f; idx[i] = i; used[i] = false; }
  for (int r = 0; r < 4; r++) {
    int best = -1;
    for (int i = 0; i < 12; i++) {
      if (used[i]) continue;
      if (best < 0 || val[i] > val[best]) best = i;
    }
    used[best] = true;
    out4[r] = idx[best];
  }
}

// ---------- MEGA: heads+state (redundant per block) -> scan -> last-block merge+attn ----------
__global__ __launch_bounds__(256, 4) void mega(
    const float* __restrict__ xi,
    const float* __restrict__ Wrq, const float* __restrict__ brq,
    const float* __restrict__ Wwv, const float* __restrict__ bwv,
    const float* __restrict__ Wig, const float* __restrict__ big,
    const float* __restrict__ Wwg, const float* __restrict__ bwg,
    const float* __restrict__ vm, const float* __restrict__ prec,
    const float* __restrict__ rw, const float* __restrict__ wwg,
    const float* __restrict__ usage,
    const float* __restrict__ lm, const float* __restrict__ rlm,
    const int* __restrict__ rp,
    const float* __restrict__ memory,
    float* blk_sv, int* blk_si,
    unsigned int* counters, unsigned long long* ukey,
    float* out) {
  int tid = threadIdx.x;
  int b = blockIdx.x / NBLK;
  int blk = blockIdx.x % NBLK;
  int base = blk * RPB;
  int wave = tid >> 6, lane = tid & 63;
  int sub = lane & 15;      // chunk within row (float4 index)
  int grp = lane >> 4;      // row within group-of-4

  // ---- LDS ----
  __shared__ float x[DDIM];
  __shared__ __align__(16) float rq_s[DDIM];
  __shared__ float wv_s[64], ig_s[CN], wg_s;
  __shared__ int ppos[CN];
  __shared__ float s_rw[CN], s_ww[CN], s_rel[CN], s_relnew[CN], s_imin[CN], s_wwnew[CN];
  __shared__ int s_guard[CN];
  __shared__ float minrel;
  __shared__ float fwd8[8], bwd8[8];
  __shared__ int fp_s[4], bp_s[4];
  __shared__ __align__(16) float upd_lds[CN][64];
  // phase 1
  __shared__ int s_lcnt;
  __shared__ int s_lpos[CN], s_lj[CN];
  __shared__ float s_lrel[CN];
  __shared__ float lsv[4][16][4];
  __shared__ int lsi[4][16][4];
  __shared__ int is_last;
  // phase 2
  __shared__ int knn_s[16];
  __shared__ float vis[CN][64];
  __shared__ float vnorm[CN], rnorm[4];
  __shared__ float sim[4][CN], pw[4][CN];

  // ================= phase 0: heads + state update (redundant, LDS-only) ===========
  x[tid] = xi[b * DDIM + tid];
  if (tid == 0) s_lcnt = 0;
  __syncthreads();
  {
    float s = brq[tid];
#pragma unroll 8
    for (int d = 0; d < DDIM; d++) s = fmaf(x[d], Wrq[d * 256 + tid], s);
    rq_s[tid] = s;
  }
  if (tid < 64) {
    float s = bwv[tid];
#pragma unroll 8
    for (int d = 0; d < DDIM; d++) s = fmaf(x[d], Wwv[d * 64 + tid], s);
    wv_s[tid] = s;
  } else if (tid < 64 + CN) {
    int o = tid - 64;
    float s = big[o];
#pragma unroll 8
    for (int d = 0; d < DDIM; d++) s = fmaf(x[d], Wig[d * CN + o], s);
    ig_s[o] = 1.f / (1.f + expf(-s));
  } else if (tid == 64 + CN) {
    float s = bwg[0];
#pragma unroll 8
    for (int d = 0; d < DDIM; d++) s = fmaf(x[d], Wwg[d], s);
    wg_s = 1.f / (1.f + expf(-s));
  }
  if (tid < CN) {
    int p = rp[b * CN + tid];
    ppos[tid] = p;
    s_rw[tid] = rw[(size_t)b * MEMN + p];
    s_ww[tid] = wwg[(size_t)b * MEMN + p];
    s_rel[tid] = usage[(size_t)b * MEMN + p];
  }
  __syncthreads();
  if (tid == 0) {
    float m = s_rel[0];
    for (int j = 1; j < CN; j++) m = fminf(m, s_rel[j]);
    minrel = m;
  }
  __syncthreads();
  if (tid < CN) {
    float u = (s_rw[tid] + s_ww[tid] > DELTA_C) ? 1.f : 0.f;
    float im = (s_rel[tid] == minrel) ? 1.f : 0.f;
    s_imin[tid] = im;
    s_relnew[tid] = u * (1.f - s_rel[tid]) + (1.f - u) * s_rel[tid];
    float igv = ig_s[tid];
    s_wwnew[tid] = wg_s * (igv * s_rw[tid] + (1.f - igv) * im);
    int g = 1;
    for (int j = tid + 1; j < CN; j++)
      if (ppos[j] == ppos[tid]) { g = 0; break; }
    s_guard[tid] = g;
  }
  __syncthreads();
  // updated memory rows -> LDS (25 rows of 64)
  for (int it = 0; it < 7; it++) {
    int j = it * 4 + wave;
    if (j < CN && s_guard[j]) {
      upd_lds[j][lane] = vm[((size_t)b * CN + j) * 64 + lane] * (1.f - s_imin[j]) +
                         s_wwnew[j] * wv_s[lane];
    }
  }
  if (tid < 8) {
    int m = tid;
    int trp_m = ppos[16 + m];
    float tww = 0.f;
    for (int j = CN - 1; j >= 0; j--)
      if (ppos[j] == trp_m) { tww = s_wwnew[j]; break; }  // always found at >=16+m
    float trw = rw[(size_t)b * MEMN + trp_m];
    float wwu;
    {
      int found = -1;
      for (int j = CN - 1; j >= 0; j--)
        if (ppos[j] == m) { found = j; break; }
      wwu = (found >= 0) ? s_wwnew[found] : wwg[(size_t)b * MEMN + m];
    }
    float lmd = (1.f - wwu) * lm[((size_t)b * MEMN + m) * 8 + m] + wwu * prec[b * 8 + m];
    float pd = 0.f;
    for (int k = 7; k >= 0; k--)
      if (ppos[16 + k] == m) { pd = prec[b * 8 + k]; break; }
    float rld = (1.f - tww) * rlm[((size_t)b * MEMN + m) * 8 + m] + tww * pd;
    fwd8[m] = lmd * trw;
    bwd8[m] = rld * trw;
  }
  __syncthreads();
  if (tid == 0) top4_of8(fwd8, fp_s);
  if (tid == 1) top4_of8(bwd8, bp_s);
  // build this block's patch list (updated rows inside [base, base+RPB))
  if (tid < CN) {
    int p = s_guard[tid] ? ppos[tid] : -1;
    if (p >= base && p < base + RPB) {
      int k = atomicAdd(&s_lcnt, 1);
      s_lpos[k] = p;
      s_lj[k] = tid;
      s_lrel[k] = s_relnew[tid];
    }
  }
  __syncthreads();

  // ================= phase 1: heavy scan ===========
  int lcnt = s_lcnt;
  const float4* q4 = (const float4*)rq_s;
  float4 qf0 = q4[0 * 16 + sub];
  float4 qf1 = q4[1 * 16 + sub];
  float4 qf2 = q4[2 * 16 + sub];
  float4 qf3 = q4[3 * 16 + sub];

  float tv0 = NEG_INF, tv1 = NEG_INF, tv2 = NEG_INF, tv3 = NEG_INF;
  int ti0 = IMAX, ti1 = IMAX, ti2 = IMAX, ti3 = IMAX;

  int rowbase = base + wave * 256;   // each wave owns 256 consecutive rows
  const float4* mp = (const float4*)memory;
  size_t lanebase = ((size_t)b * MEMN + rowbase) * 16 + (size_t)grp * 16 + sub;

#pragma unroll 4
  for (int it = 0; it < 64; it++) {
    int m = rowbase + it * 4 + grp;
    float4 xx = mp[lanebase + (size_t)it * 64];
    if (lcnt) {
      for (int k = 0; k < lcnt; k++)
        if (m == s_lpos[k])
          xx = ((const float4*)upd_lds[s_lj[k]])[sub];
    }
    float d0 = fmaf(xx.x, qf0.x, fmaf(xx.y, qf0.y, fmaf(xx.z, qf0.z, xx.w * qf0.w)));
    float d1 = fmaf(xx.x, qf1.x, fmaf(xx.y, qf1.y, fmaf(xx.z, qf1.z, xx.w * qf1.w)));
    float d2 = fmaf(xx.x, qf2.x, fmaf(xx.y, qf2.y, fmaf(xx.z, qf2.z, xx.w * qf2.w)));
    float d3 = fmaf(xx.x, qf3.x, fmaf(xx.y, qf3.y, fmaf(xx.z, qf3.z, xx.w * qf3.w)));
    float sq = fmaf(xx.x, xx.x, fmaf(xx.y, xx.y, fmaf(xx.z, xx.z, xx.w * xx.w)));
#pragma unroll
    for (int off = 1; off < 16; off <<= 1) {
      d0 += __shfl_xor(d0, off);
      d1 += __shfl_xor(d1, off);
      d2 += __shfl_xor(d2, off);
      d3 += __shfl_xor(d3, off);
      sq += __shfl_xor(sq, off);
    }
    float d = (sub == 0) ? d0 : (sub == 1) ? d1 : (sub == 2) ? d2 : d3;
    float s = 2.f * d - sq;
    if (sub < 4) {
      if (s > tv3) {
        tv3 = s; ti3 = m;
        if (tv3 > tv2) { float t = tv2; tv2 = tv3; tv3 = t; int u = ti2; ti2 = ti3; ti3 = u; }
        if (tv2 > tv1) { float t = tv1; tv1 = tv2; tv2 = t; int u = ti1; ti1 = ti2; ti2 = u; }
        if (tv1 > tv0) { float t = tv0; tv0 = tv1; tv1 = t; int u = ti0; ti0 = ti1; ti1 = u; }
      }
    }
  }

  if (sub < 4) {
    int slot = wave * 4 + grp;
    lsv[sub][slot][0] = tv0; lsi[sub][slot][0] = ti0;
    lsv[sub][slot][1] = tv1; lsi[sub][slot][1] = ti1;
    lsv[sub][slot][2] = tv2; lsi[sub][slot][2] = ti2;
    lsv[sub][slot][3] = tv3; lsi[sub][slot][3] = ti3;
  }
  __syncthreads();
  // wave-parallel merge: wave w merges query w's 64 candidates (value desc, index asc)
  {
    int w = wave;
    float v = lsv[w][lane >> 2][lane & 3];
    int i = lsi[w][lane >> 2][lane & 3];
    size_t o = (((size_t)b * 4 + w) * NBLK + blk) * 4;
    for (int round = 0; round < 4; round++) {
      float rv = v; int ri = i; int rt = lane;
      wave_reduce_max(rv, ri, rt);
      rv = __shfl(rv, 0); ri = __shfl(ri, 0); rt = __shfl(rt, 0);
      if (lane == 0) { blk_sv[o + round] = rv; blk_si[o + round] = ri; }
      if (lane == rt) { v = NEG_INF; i = IMAX; }
    }
  }

  // usage argmin: batch 0 only (reference uses least_used[0,0]); publish via packed atomicMax
  if (b == 0) {
    const float4* u4 = (const float4*)(usage + base);
    float4 uu = u4[tid];
    int mb = base + tid * 4;
    if (lcnt) {
      for (int k = 0; k < lcnt; k++) {
        int d = s_lpos[k] - mb;
        if ((unsigned)d < 4u) {
          float rv = s_lrel[k];
          if (d == 0) uu.x = rv;
          else if (d == 1) uu.y = rv;
          else if (d == 2) uu.z = rv;
          else uu.w = rv;
        }
      }
    }
    float uv = uu.x; int uix = mb;
    if (uu.y < uv) { uv = uu.y; uix = mb + 1; }
    if (uu.z < uv) { uv = uu.z; uix = mb + 2; }
    if (uu.w < uv) { uv = uu.w; uix = mb + 3; }
    float rvv; int rii, rtt;
    block_argmax256(tid, -uv, uix, tid, rvv, rii, rtt);
    if (tid == 0) {
      // inverted key: max over (0xFFFFFFFF-bits(val) , 0xFFFFFFFF-idx) == (min val, min idx)
      unsigned vb = __float_as_uint(-rvv);   // -rvv = min usage value (non-negative)
      unsigned long long key =
          ((unsigned long long)(0xFFFFFFFFu - vb) << 32) | (0xFFFFFFFFu - (unsigned)rii);
      atomicMax(ukey, key);
    }
  }

  // ================= completion: last block of batch b does merge+attn ===========
  __syncthreads();
  __threadfence();
  if (tid == 0) is_last = (atomicAdd(&counters[b], 1u) == (unsigned)(NBLK - 1));
  __syncthreads();
  if (!is_last) return;
  if (tid == 0 && b != 0) {
    while (atomicAdd(&counters[0], 0u) < (unsigned)NBLK) {}
  }
  __syncthreads();
  __threadfence();

  // phase A: wave w merges query w over its 512 block-candidates
  {
    int r = wave;
    size_t o = (size_t)(b * 4 + r) * NBLK * 4;
    float av0 = NEG_INF, av1 = NEG_INF, av2 = NEG_INF, av3 = NEG_INF;
    int ai0 = IMAX, ai1 = IMAX, ai2 = IMAX, ai3 = IMAX;
#pragma unroll
    for (int j = 0; j < 8; j++) {       // ascending entry index per lane
      float s = blk_sv[o + j * 64 + lane];
      int m = blk_si[o + j * 64 + lane];
      if (s > av3) {
        av3 = s; ai3 = m;
        if (av3 > av2) { float t = av2; av2 = av3; av3 = t; int u = ai2; ai2 = ai3; ai3 = u; }
        if (av2 > av1) { float t = av1; av1 = av2; av2 = t; int u = ai1; ai1 = ai2; ai2 = u; }
        if (av1 > av0) { float t = av0; av0 = av1; av1 = t; int u = ai0; ai0 = ai1; ai1 = u; }
      }
    }
    for (int round = 0; round < 4; round++) {
      float rv = av0; int ri = ai0; int rt = lane;
      wave_reduce_max(rv, ri, rt);
      rv = __shfl(rv, 0); ri = __shfl(ri, 0); rt = __shfl(rt, 0);
      if (lane == 0) knn_s[r * 4 + round] = ri;
      if (lane == rt) {
        av0 = av1; ai0 = ai1; av1 = av2; ai1 = ai2;
        av2 = av3; ai2 = ai3; av3 = NEG_INF; ai3 = IMAX;
      }
    }
  }
  __syncthreads();

  // phase C: gather (with LDS update patch) + cosine attention
  int L;
  {
    unsigned long long k = *(volatile unsigned long long*)ukey;
    L = (int)(0xFFFFFFFFu - (unsigned)(k & 0xFFFFFFFFull));
  }
  __shared__ int cpos[CN];
  __shared__ int ovr[CN];
  if (tid < CN) {
    int v;
    if (tid < 16) v = knn_s[tid];
    else if (tid < 20) v = fp_s[tid - 16];
    else if (tid < 24) v = bp_s[tid - 20];
    else v = CN + 1;
    v = min(v, L);
    v = max(v, 0);
    cpos[tid] = v;
  }
  __syncthreads();
  if (tid < CN) {
    int o = -1;
    for (int j = 0; j < CN; j++)
      if (s_guard[j] && ppos[j] == cpos[tid]) o = j;
    ovr[tid] = o;
  }
  __syncthreads();
  for (int it = 0; it < 7; it++) {
    int j = it * 4 + wave;
    if (j < CN) {
      int o = ovr[j];
      vis[j][lane] = (o >= 0)
          ? upd_lds[o][lane]
          : memory[((size_t)b * MEMN + cpos[j]) * 64 + lane];
    }
  }
  __syncthreads();
  if (tid < CN) {
    float s = 0.f;
    for (int k = 0; k < 64; k++) s = fmaf(vis[tid][k], vis[tid][k], s);
    vnorm[tid] = sqrtf(s) + EPS_C;
  }
  if (tid >= 32 && tid < 36) {
    int r = tid - 32;
    float s = 0.f;
    for (int k = 0; k < 64; k++) s = fmaf(rq_s[r * 64 + k], rq_s[r * 64 + k], s);
    rnorm[r] = sqrtf(s) + EPS_C;
  }
  __syncthreads();
  if (tid < 4 * CN) {
    int r = tid / CN, c = tid % CN;
    float s = 0.f;
    for (int k = 0; k < 64; k++) s = fmaf(rq_s[r * 64 + k], vis[c][k], s);
    sim[r][c] = s / (rnorm[r] * vnorm[c]);
  }
  __syncthreads();
  if (tid < 4) {
    int r = tid;
    float mx = NEG_INF;
    for (int c = 0; c < CN; c++) mx = fmaxf(mx, sim[r][c]);
    float sum = 0.f;
    for (int c = 0; c < CN; c++) { float e = expf(sim[r][c] - mx); pw[r][c] = e; sum += e; }
    float inv = 1.f / sum;
    for (int c = 0; c < CN; c++) pw[r][c] *= inv;
  }
  __syncthreads();
  {
    int r = wave, w = lane;
    float s = 0.f;
    for (int c = 0; c < CN; c++) s = fmaf(pw[r][c], vis[c][w], s);
    out[(size_t)b * 256 + tid] = s;
  }
}

// ---------- launch ----------
extern "C" void kernel_launch(void* const* d_in, const int* in_sizes, int n_in,
                              void* d_out, int out_size, void* d_ws, size_t ws_size,
                              hipStream_t stream) {
  const float* xi = (const float*)d_in[0];
  const float* memory = (const float*)d_in[1];   // read-only (pure launch)
  const float* vm = (const float*)d_in[2];
  const float* lm = (const float*)d_in[3];
  const float* rlm = (const float*)d_in[4];
  const float* prec = (const float*)d_in[5];
  const float* rw = (const float*)d_in[6];
  const float* wwg = (const float*)d_in[7];
  const float* usage = (const float*)d_in[8];
  // d_in[9] least_used_mem: unused by reference
  const int* rp = (const int*)d_in[10];
  const float* Wrq = (const float*)d_in[11];
  const float* brq = (const float*)d_in[12];
  const float* Wwv = (const float*)d_in[13];
  const float* bwv = (const float*)d_in[14];
  const float* Wig = (const float*)d_in[15];
  const float* big = (const float*)d_in[16];
  const float* Wwg = (const float*)d_in[17];
  const float* bwg = (const float*)d_in[18];
  float* out = (float*)d_out;

  // workspace carve:
  //   [0,32)   counters[8]  (zeroed)
  //   [32,40)  ukey         (zeroed; inverted-key atomicMax)
  //   [64,...) blk_sv, blk_si
  unsigned int* counters = (unsigned int*)d_ws;
  unsigned long long* ukey = (unsigned long long*)((char*)d_ws + 32);
  float* blk_sv = (float*)((char*)d_ws + 64);
  int* blk_si = (int*)(blk_sv + (size_t)BN * 4 * NBLK * 4);

  hipMemsetAsync(d_ws, 0, 64, stream);
  hipLaunchKernelGGL(mega, dim3(BN * NBLK), dim3(256), 0, stream,
                     xi, Wrq, brq, Wwv, bwv, Wig, big, Wwg, bwg,
                     vm, prec, rw, wwg, usage, lm, rlm, rp, memory,
                     blk_sv, blk_si, counters, ukey, out);
}

// Round 4
// 489.421 us; speedup vs baseline: 1.2681x; 1.2681x over previous
//
#include <hip/hip_runtime.h>
#include <math.h>

#define BN 8
#define DDIM 256
#define MEMN 131072
#define CWN 64
#define RN 4
#define CN 25
#define DELTA_C 0.005f
#define EPS_C 1e-6f
#define RPB 1024
#define NBLK (MEMN / RPB)   // 128
#define NEG_INF (-3.402823466e38f)
#define IMAX 0x7fffffff
#define UPD_STRIDE 32       // padded stride for per-batch update lists

// ---------- helpers ----------

__device__ inline void wave_reduce_max(float& v, int& i, int& t) {
#pragma unroll
  for (int off = 32; off; off >>= 1) {
    float ov = __shfl_down(v, off);
    int oi = __shfl_down(i, off);
    int ot = __shfl_down(t, off);
    if (ov > v || (ov == v && oi < i)) { v = ov; i = oi; t = ot; }
  }
}

// block of 256 threads; returns (max value, min index on tie) + winning tid
__device__ inline void block_argmax256(int tid, float v, int i, int t,
                                       float& rv, int& ri, int& rt) {
  __shared__ float sv[4];
  __shared__ int si[4], st[4];
  __shared__ float bv;
  __shared__ int bi, bt;
  wave_reduce_max(v, i, t);
  if ((tid & 63) == 0) { int w = tid >> 6; sv[w] = v; si[w] = i; st[w] = t; }
  __syncthreads();
  if (tid == 0) {
    float xv = sv[0]; int xi = si[0], xt = st[0];
#pragma unroll
    for (int w = 1; w < 4; w++)
      if (sv[w] > xv || (sv[w] == xv && si[w] < xi)) { xv = sv[w]; xi = si[w]; xt = st[w]; }
    bv = xv; bi = xi; bt = xt;
  }
  __syncthreads();
  rv = bv; ri = bi; rt = bt;
  __syncthreads();
}

// top-4 indices of 8 nonneg values padded with zero-candidates at idx 8..11
// (JAX top_k: value desc, index asc on ties)
__device__ inline void top4_of8(const float* v8, int* out4) {
  float val[12]; int idx[12]; bool used[12];
#pragma unroll
  for (int i = 0; i < 12; i++) { val[i] = (i < 8) ? v8[i] : 0.f; idx[i] = i; used[i] = false; }
  for (int r = 0; r < 4; r++) {
    int best = -1;
    for (int i = 0; i < 12; i++) {
      if (used[i]) continue;
      if (best < 0 || val[i] > val[best]) best = i;
    }
    used[best] = true;
    out4[r] = idx[best];
  }
}

__device__ inline float dot4(float4 a, float4 b) {
  return fmaf(a.x, b.x, fmaf(a.y, b.y, fmaf(a.z, b.z, a.w * b.w)));
}

// ---------- K12: MLP heads + per-batch state update (fused) ----------
__global__ __launch_bounds__(256) void k12_heads_state(
    const float* __restrict__ xi,
    const float* __restrict__ Wrq, const float* __restrict__ brq,
    const float* __restrict__ Wwv, const float* __restrict__ bwv,
    const float* __restrict__ Wig, const float* __restrict__ big,
    const float* __restrict__ Wwg, const float* __restrict__ bwg,
    const float* __restrict__ vm, const float* __restrict__ prec,
    const float* __restrict__ rw, const float* __restrict__ wwg,
    const float* __restrict__ usage,
    const float* __restrict__ lm, const float* __restrict__ rlm,
    const int* __restrict__ rp,
    float* rq, int* fp, int* bp,
    int* upd_pos, float* upd_rel, float* upd_mem) {
  int b = blockIdx.x, tid = threadIdx.x;
  __shared__ float x[DDIM];
  __shared__ float wv_s[64], ig_s[CN], wg_s;
  __shared__ int pos[CN];
  __shared__ float s_rw[CN], s_ww[CN], s_rel[CN], s_relnew[CN], s_imin[CN], s_wwnew[CN];
  __shared__ int s_guard[CN];
  __shared__ float minrel;
  __shared__ float fwd8[8], bwd8[8];

  x[tid] = xi[b * DDIM + tid];
  __syncthreads();
  // --- heads ---
  {
    float s = brq[tid];
#pragma unroll 8
    for (int d = 0; d < DDIM; d++) s = fmaf(x[d], Wrq[d * 256 + tid], s);
    rq[b * 256 + tid] = s;
  }
  if (tid < 64) {
    float s = bwv[tid];
#pragma unroll 8
    for (int d = 0; d < DDIM; d++) s = fmaf(x[d], Wwv[d * 64 + tid], s);
    wv_s[tid] = s;
  } else if (tid < 64 + CN) {
    int o = tid - 64;
    float s = big[o];
#pragma unroll 8
    for (int d = 0; d < DDIM; d++) s = fmaf(x[d], Wig[d * CN + o], s);
    ig_s[o] = 1.f / (1.f + expf(-s));
  } else if (tid == 64 + CN) {
    float s = bwg[0];
#pragma unroll 8
    for (int d = 0; d < DDIM; d++) s = fmaf(x[d], Wwg[d], s);
    wg_s = 1.f / (1.f + expf(-s));
  }
  // --- state update ---
  if (tid < CN) {
    int p = rp[b * CN + tid];
    pos[tid] = p;
    s_rw[tid] = rw[(size_t)b * MEMN + p];
    s_ww[tid] = wwg[(size_t)b * MEMN + p];
    s_rel[tid] = usage[(size_t)b * MEMN + p];
  }
  __syncthreads();
  if (tid == 0) {
    float m = s_rel[0];
    for (int j = 1; j < CN; j++) m = fminf(m, s_rel[j]);
    minrel = m;
  }
  __syncthreads();
  if (tid < CN) {
    float u = (s_rw[tid] + s_ww[tid] > DELTA_C) ? 1.f : 0.f;
    float im = (s_rel[tid] == minrel) ? 1.f : 0.f;
    s_imin[tid] = im;
    s_relnew[tid] = u * (1.f - s_rel[tid]) + (1.f - u) * s_rel[tid];
    float igv = ig_s[tid];
    s_wwnew[tid] = wg_s * (igv * s_rw[tid] + (1.f - igv) * im);
    int g = 1;
    for (int j = tid + 1; j < CN; j++)
      if (pos[j] == pos[tid]) { g = 0; break; }
    s_guard[tid] = g;
  }
  __syncthreads();
  // publish sparse updates to workspace (last-write-wins guard preserved)
  if (tid < CN) {
    upd_pos[b * UPD_STRIDE + tid] = s_guard[tid] ? pos[tid] : -1;
    upd_rel[b * UPD_STRIDE + tid] = s_relnew[tid];
  }
  // updated memory rows: 25 rows of 64 -> workspace
  for (int it = 0; it < 7; it++) {
    int j = it * 4 + (tid >> 6);
    int lane = tid & 63;
    if (j < CN && s_guard[j]) {
      float v = vm[((size_t)b * CN + j) * 64 + lane] * (1.f - s_imin[j]) +
                s_wwnew[j] * wv_s[lane];
      upd_mem[((size_t)b * CN + j) * 64 + lane] = v;
    }
  }
  __syncthreads();
  if (tid < 8) {
    int m = tid;
    int trp_m = pos[16 + m];
    float tww = 0.f;
    for (int j = CN - 1; j >= 0; j--)
      if (pos[j] == trp_m) { tww = s_wwnew[j]; break; }  // always found at >=16+m
    float trw = rw[(size_t)b * MEMN + trp_m];
    float wwu;
    {
      int found = -1;
      for (int j = CN - 1; j >= 0; j--)
        if (pos[j] == m) { found = j; break; }
      wwu = (found >= 0) ? s_wwnew[found] : wwg[(size_t)b * MEMN + m];
    }
    float lmd = (1.f - wwu) * lm[((size_t)b * MEMN + m) * 8 + m] + wwu * prec[b * 8 + m];
    float pd = 0.f;
    for (int k = 7; k >= 0; k--)
      if (pos[16 + k] == m) { pd = prec[b * 8 + k]; break; }
    float rld = (1.f - tww) * rlm[((size_t)b * MEMN + m) * 8 + m] + tww * pd;
    fwd8[m] = lmd * trw;
    bwd8[m] = rld * trw;
  }
  __syncthreads();
  if (tid == 0) top4_of8(fwd8, &fp[b * 4]);
  if (tid == 1) top4_of8(bwd8, &bp[b * 4]);
}

// ---------- K3: heavy scan, 4-lane-per-row (minimal cross-lane traffic) ----------
// Lane (r4 = lane>>2, s4 = lane&3) owns one row per row-block and the
// contiguous 64B quarter [s4*16 .. s4*16+15] floats of it. Dot-product tree
// (t0+t1)+(t2+t3) then xor 1,2 is bit-identical to the old chunk-per-lane
// xor 1,2,4,8 tree, so scores match the previous (absmax==0) kernel exactly.
__global__ __launch_bounds__(256, 4) void k3_scan(
    const float* __restrict__ memory, const float* __restrict__ usage,
    const float* __restrict__ rq,
    const int* __restrict__ upd_pos, const float* __restrict__ upd_rel,
    const float* __restrict__ upd_mem,
    float* blk_sv, int* blk_si, float* blk_uv, int* blk_ui) {
  int tid = threadIdx.x;
  int b = blockIdx.x / NBLK;
  int blk = blockIdx.x % NBLK;
  int base = blk * RPB;
  int wave = tid >> 6, lane = tid & 63;
  int r4 = lane >> 2, s4 = lane & 3;

  // build local list of updated rows that fall in this block's row range
  __shared__ int s_lcnt;
  __shared__ int s_lpos[CN], s_lj[CN];
  __shared__ float s_lrel[CN];
  if (tid == 0) s_lcnt = 0;
  __syncthreads();
  if (tid < CN) {
    int p = upd_pos[b * UPD_STRIDE + tid];
    if (p >= base && p < base + RPB) {
      int k = atomicAdd(&s_lcnt, 1);
      s_lpos[k] = p;
      s_lj[k] = tid;
      s_lrel[k] = upd_rel[b * UPD_STRIDE + tid];
    }
  }
  __syncthreads();
  int lcnt = s_lcnt;
  const float4* upd4 = (const float4*)upd_mem;

  // q fragments: lane needs all 4 queries at its 4 quarter chunks
  const float4* q4 = (const float4*)(rq + b * 256);
  float4 qf[4][4];  // [query][j], chunk index = s4*4+j
#pragma unroll
  for (int q = 0; q < 4; q++)
#pragma unroll
    for (int j = 0; j < 4; j++)
      qf[q][j] = q4[q * 16 + s4 * 4 + j];

  // per-lane top-4 for query s4 over this lane's 16 rows
  float tv0 = NEG_INF, tv1 = NEG_INF, tv2 = NEG_INF, tv3 = NEG_INF;
  int ti0 = IMAX, ti1 = IMAX, ti2 = IMAX, ti3 = IMAX;

  int rowstart = base + wave * 256;   // each wave owns 256 consecutive rows
  const float4* mp = (const float4*)memory;

#pragma unroll 2
  for (int bi = 0; bi < 16; bi++) {
    int m = rowstart + bi * 16 + r4;
    size_t a = ((size_t)b * MEMN + m) * 16 + s4 * 4;
    float4 x0 = mp[a + 0];
    float4 x1 = mp[a + 1];
    float4 x2 = mp[a + 2];
    float4 x3 = mp[a + 3];
    if (lcnt) {
      for (int k = 0; k < lcnt; k++)
        if (m == s_lpos[k]) {
          const float4* u = &upd4[((size_t)b * CN + s_lj[k]) * 16 + s4 * 4];
          x0 = u[0]; x1 = u[1]; x2 = u[2]; x3 = u[3];
        }
    }
    float d0 = (dot4(x0, qf[0][0]) + dot4(x1, qf[0][1])) +
               (dot4(x2, qf[0][2]) + dot4(x3, qf[0][3]));
    float d1 = (dot4(x0, qf[1][0]) + dot4(x1, qf[1][1])) +
               (dot4(x2, qf[1][2]) + dot4(x3, qf[1][3]));
    float d2 = (dot4(x0, qf[2][0]) + dot4(x1, qf[2][1])) +
               (dot4(x2, qf[2][2]) + dot4(x3, qf[2][3]));
    float d3 = (dot4(x0, qf[3][0]) + dot4(x1, qf[3][1])) +
               (dot4(x2, qf[3][2]) + dot4(x3, qf[3][3]));
    float sq = (dot4(x0, x0) + dot4(x1, x1)) +
               (dot4(x2, x2) + dot4(x3, x3));
    // 2-round reduce over the 4-lane group (completes the old 4-round tree)
#pragma unroll
    for (int off = 1; off < 4; off <<= 1) {
      d0 += __shfl_xor(d0, off);
      d1 += __shfl_xor(d1, off);
      d2 += __shfl_xor(d2, off);
      d3 += __shfl_xor(d3, off);
      sq += __shfl_xor(sq, off);
    }
    float d = (s4 == 0) ? d0 : (s4 == 1) ? d1 : (s4 == 2) ? d2 : d3;
    float s = 2.f * d - sq;
    if (s > tv3) {
      tv3 = s; ti3 = m;
      if (tv3 > tv2) { float t = tv2; tv2 = tv3; tv3 = t; int u = ti2; ti2 = ti3; ti3 = u; }
      if (tv2 > tv1) { float t = tv1; tv1 = tv2; tv2 = t; int u = ti1; ti1 = ti2; ti2 = u; }
      if (tv1 > tv0) { float t = tv0; tv0 = tv1; tv1 = t; int u = ti0; ti0 = ti1; ti1 = u; }
    }
  }

  // dump per-lane lists: per query, 64 slots (4 waves x 16 r4)
  __shared__ float lsv[4][64][4];
  __shared__ int lsi[4][64][4];
  {
    int slot = wave * 16 + r4;
    lsv[s4][slot][0] = tv0; lsi[s4][slot][0] = ti0;
    lsv[s4][slot][1] = tv1; lsi[s4][slot][1] = ti1;
    lsv[s4][slot][2] = tv2; lsi[s4][slot][2] = ti2;
    lsv[s4][slot][3] = tv3; lsi[s4][slot][3] = ti3;
  }
  __syncthreads();
  // wave-parallel merge: wave w merges query w's 64 sorted 4-lists (tournament)
  {
    int w = wave;
    float v0 = lsv[w][lane][0], v1 = lsv[w][lane][1],
          v2 = lsv[w][lane][2], v3 = lsv[w][lane][3];
    int i0 = lsi[w][lane][0], i1 = lsi[w][lane][1],
        i2 = lsi[w][lane][2], i3 = lsi[w][lane][3];
    size_t o = (((size_t)b * 4 + w) * NBLK + blk) * 4;
    for (int round = 0; round < 4; round++) {
      float rv = v0; int ri = i0; int rt = lane;
      wave_reduce_max(rv, ri, rt);
      rv = __shfl(rv, 0); ri = __shfl(ri, 0); rt = __shfl(rt, 0);
      if (lane == 0) { blk_sv[o + round] = rv; blk_si[o + round] = ri; }
      if (lane == rt) {
        v0 = v1; i0 = i1; v1 = v2; i1 = i2;
        v2 = v3; i2 = i3; v3 = NEG_INF; i3 = IMAX;
      }
    }
  }

  // usage argmin: only batch 0 is ever consumed (reference uses least_used[0,0])
  if (b == 0) {
    const float4* u4 = (const float4*)(usage + base);
    float4 uu = u4[tid];
    int mb = base + tid * 4;
    if (lcnt) {
      for (int k = 0; k < lcnt; k++) {
        int d = s_lpos[k] - mb;
        if ((unsigned)d < 4u) {
          float rv = s_lrel[k];
          if (d == 0) uu.x = rv;
          else if (d == 1) uu.y = rv;
          else if (d == 2) uu.z = rv;
          else uu.w = rv;
        }
      }
    }
    float uv = uu.x; int uix = mb;
    if (uu.y < uv) { uv = uu.y; uix = mb + 1; }
    if (uu.z < uv) { uv = uu.z; uix = mb + 2; }
    if (uu.w < uv) { uv = uu.w; uix = mb + 3; }
    float rvv; int rii, rtt;
    block_argmax256(tid, -uv, uix, tid, rvv, rii, rtt);
    if (tid == 0) {
      blk_uv[blk] = -rvv;
      blk_ui[blk] = rii;
    }
  }
}

// ---------- K45: merge + gather + cosine attention (fused) ----------
__global__ __launch_bounds__(256) void k45_merge_attn(
    const float* __restrict__ memory, const float* __restrict__ rq,
    const float* __restrict__ blk_sv, const int* __restrict__ blk_si,
    const float* __restrict__ blk_uv, const int* __restrict__ blk_ui,
    const int* __restrict__ fp, const int* __restrict__ bp,
    const int* __restrict__ upd_pos, const float* __restrict__ upd_mem,
    float* out) {
  int b = blockIdx.x, tid = threadIdx.x;
  int wave = tid >> 6, lane = tid & 63;
  __shared__ int knn_s[16];
  __shared__ int sL;
  __shared__ int pos[CN];
  __shared__ int supd[CN];
  __shared__ int ovr[CN];
  __shared__ float vis[CN][64];
  __shared__ float vnorm[CN];
  __shared__ float rnorm[4];
  __shared__ float sim[4][CN];
  __shared__ float pw[4][CN];
  __shared__ float qs[4][64];

  // phase A: wave w merges query w over its 512 block-candidates
  {
    int r = wave;
    size_t o = (size_t)(b * 4 + r) * NBLK * 4;
    float tv0 = NEG_INF, tv1 = NEG_INF, tv2 = NEG_INF, tv3 = NEG_INF;
    int ti0 = IMAX, ti1 = IMAX, ti2 = IMAX, ti3 = IMAX;
#pragma unroll
    for (int j = 0; j < 8; j++) {       // ascending entry index per lane
      float s = blk_sv[o + j * 64 + lane];
      int m = blk_si[o + j * 64 + lane];
      if (s > tv3) {
        tv3 = s; ti3 = m;
        if (tv3 > tv2) { float t = tv2; tv2 = tv3; tv3 = t; int u = ti2; ti2 = ti3; ti3 = u; }
        if (tv2 > tv1) { float t = tv1; tv1 = tv2; tv2 = t; int u = ti1; ti1 = ti2; ti2 = u; }
        if (tv1 > tv0) { float t = tv0; tv0 = tv1; tv1 = t; int u = ti0; ti0 = ti1; ti1 = u; }
      }
    }
    for (int round = 0; round < 4; round++) {
      float rv = tv0; int ri = ti0; int rt = lane;
      wave_reduce_max(rv, ri, rt);
      rv = __shfl(rv, 0); ri = __shfl(ri, 0); rt = __shfl(rt, 0);
      if (lane == 0) knn_s[r * 4 + round] = ri;
      if (lane == rt) {
        tv0 = tv1; ti0 = ti1; tv1 = tv2; ti1 = ti2;
        tv2 = tv3; ti2 = ti3; tv3 = NEG_INF; ti3 = IMAX;
      }
    }
  }
  // phase B: batch-0 least-used (wave 0 only; 128 entries)
  if (wave == 0) {
    float u0 = blk_uv[lane], u1 = blk_uv[64 + lane];
    int i0 = blk_ui[lane], i1 = blk_ui[64 + lane];
    float v; int i;
    if (u1 < u0 || (u1 == u0 && i1 < i0)) { v = u1; i = i1; } else { v = u0; i = i0; }
    float rv = -v; int ri = i; int rt = lane;
    wave_reduce_max(rv, ri, rt);
    if (lane == 0) sL = ri;
  }
  qs[tid >> 6][tid & 63] = rq[b * 256 + tid];
  __syncthreads();

  // phase C: gather (with update patch) + cosine attention
  int L = sL;
  if (tid < CN) {
    supd[tid] = upd_pos[b * UPD_STRIDE + tid];
    int v;
    if (tid < 16) v = knn_s[tid];
    else if (tid < 20) v = fp[b * 4 + tid - 16];
    else if (tid < 24) v = bp[b * 4 + tid - 20];
    else v = CN + 1;
    v = min(v, L);
    v = max(v, 0);
    pos[tid] = v;
  }
  __syncthreads();
  if (tid < CN) {
    int o = -1;
    for (int j = 0; j < CN; j++)
      if (supd[j] == pos[tid]) o = j;   // supd==-1 never matches (pos>=0)
    ovr[tid] = o;
  }
  __syncthreads();
  for (int it = 0; it < 7; it++) {
    int j = it * 4 + (tid >> 6);
    int ln = tid & 63;
    if (j < CN) {
      int o = ovr[j];
      vis[j][ln] = (o >= 0)
          ? upd_mem[((size_t)b * CN + o) * 64 + ln]
          : memory[((size_t)b * MEMN + pos[j]) * 64 + ln];
    }
  }
  __syncthreads();
  if (tid < CN) {
    float s = 0.f;
    for (int k = 0; k < 64; k++) s = fmaf(vis[tid][k], vis[tid][k], s);
    vnorm[tid] = sqrtf(s) + EPS_C;
  }
  if (tid >= 32 && tid < 36) {
    int r = tid - 32;
    float s = 0.f;
    for (int k = 0; k < 64; k++) s = fmaf(qs[r][k], qs[r][k], s);
    rnorm[r] = sqrtf(s) + EPS_C;
  }
  __syncthreads();
  if (tid < 4 * CN) {
    int r = tid / CN, c = tid % CN;
    float s = 0.f;
    for (int k = 0; k < 64; k++) s = fmaf(qs[r][k], vis[c][k], s);
    sim[r][c] = s / (rnorm[r] * vnorm[c]);
  }
  __syncthreads();
  if (tid < 4) {
    int r = tid;
    float mx = NEG_INF;
    for (int c = 0; c < CN; c++) mx = fmaxf(mx, sim[r][c]);
    float sum = 0.f;
    for (int c = 0; c < CN; c++) { float e = expf(sim[r][c] - mx); pw[r][c] = e; sum += e; }
    float inv = 1.f / sum;
    for (int c = 0; c < CN; c++) pw[r][c] *= inv;
  }
  __syncthreads();
  {
    int r = tid >> 6, w = tid & 63;
    float s = 0.f;
    for (int c = 0; c < CN; c++) s = fmaf(pw[r][c], vis[c][w], s);
    out[(size_t)b * 256 + tid] = s;
  }
}

// ---------- launch ----------
extern "C" void kernel_launch(void* const* d_in, const int* in_sizes, int n_in,
                              void* d_out, int out_size, void* d_ws, size_t ws_size,
                              hipStream_t stream) {
  const float* xi = (const float*)d_in[0];
  const float* memory = (const float*)d_in[1];   // read-only (pure launch)
  const float* vm = (const float*)d_in[2];
  const float* lm = (const float*)d_in[3];
  const float* rlm = (const float*)d_in[4];
  const float* prec = (const float*)d_in[5];
  const float* rw = (const float*)d_in[6];
  const float* wwg = (const float*)d_in[7];
  const float* usage = (const float*)d_in[8];
  // d_in[9] least_used_mem: unused by reference
  const int* rp = (const int*)d_in[10];
  const float* Wrq = (const float*)d_in[11];
  const float* brq = (const float*)d_in[12];
  const float* Wwv = (const float*)d_in[13];
  const float* bwv = (const float*)d_in[14];
  const float* Wig = (const float*)d_in[15];
  const float* big = (const float*)d_in[16];
  const float* Wwg = (const float*)d_in[17];
  const float* bwg = (const float*)d_in[18];
  float* out = (float*)d_out;

  // workspace carve (upd_mem 16B aligned: offset 2048 floats = 8192 B)
  float* f = (float*)d_ws;
  float* rq_w = f;      f += BN * 256;                 // 2048
  float* upd_mem_w = f; f += (size_t)BN * CN * 64;     // 12800
  float* upd_rel_w = f; f += BN * UPD_STRIDE;
  float* blk_sv = f;    f += (size_t)BN * 4 * NBLK * 4;
  float* blk_uv = f;    f += NBLK;                     // batch 0 only
  int* ip = (int*)f;
  int* upd_pos_w = ip;  ip += BN * UPD_STRIDE;
  int* fp_w = ip;       ip += BN * 4;
  int* bp_w = ip;       ip += BN * 4;
  int* blk_si = ip;     ip += (size_t)BN * 4 * NBLK * 4;
  int* blk_ui = ip;     ip += NBLK;                    // batch 0 only

  hipLaunchKernelGGL(k12_heads_state, dim3(BN), dim3(256), 0, stream,
                     xi, Wrq, brq, Wwv, bwv, Wig, big, Wwg, bwg,
                     vm, prec, rw, wwg, usage, lm, rlm, rp,
                     rq_w, fp_w, bp_w, upd_pos_w, upd_rel_w, upd_mem_w);
  hipLaunchKernelGGL(k3_scan, dim3(BN * NBLK), dim3(256), 0, stream,
                     memory, usage, rq_w, upd_pos_w, upd_rel_w, upd_mem_w,
                     blk_sv, blk_si, blk_uv, blk_ui);
  hipLaunchKernelGGL(k45_merge_attn, dim3(BN), dim3(256), 0, stream,
                     memory, rq_w, blk_sv, blk_si, blk_uv, blk_ui,
                     fp_w, bp_w, upd_pos_w, upd_mem_w, out);
}